// Round 2
// baseline (1577.321 us; speedup 1.0000x reference)
//
#include <hip/hip_runtime.h>
#include <math.h>

#define NCB 7
#define CBK 1024
#define CD  8
#define BB  16
#define DD  256
#define TT  8192

typedef float v2f __attribute__((ext_vector_type(2)));
typedef float v4f __attribute__((ext_vector_type(4)));

static constexpr size_t ZQN  = (size_t)BB * DD * TT;   // 33554432
static constexpr size_t IDX0 = ZQN + 2;

// ---------------------------------------------------------------- prep ------
// wTin [NCB][DD][CD], wTout [NCB][DD][CD]
// cbp: paired records. For codebook i, pair q (codes k0=2q, k1=2q+1):
//   rec[2c+h] = cbn_{k0+h}[c]  (c=0..7),  rec[16+h] = c2_{k0+h},  stride 32 floats.
__global__ void rvq_prep(const float* __restrict__ in_v, const float* __restrict__ in_g,
                         const float* __restrict__ out_v, const float* __restrict__ out_g,
                         const float* __restrict__ cb,
                         float* __restrict__ wTin, float* __restrict__ wTout,
                         float* __restrict__ cbp, double* __restrict__ lossAcc)
{
#pragma clang fp contract(off)
  int gid = blockIdx.x * blockDim.x + threadIdx.x;
  if (gid == 0) *lossAcc = 0.0;
  if (gid < NCB*DD*CD) {
    int i = gid / (DD*CD); int rem = gid % (DD*CD); int d = rem / CD; int c = rem % CD;
    const float* vrow = in_v + ((size_t)i*CD + c) * DD;   // in_v [NCB][CD][DD]
    double acc = 0.0;
    for (int q = 0; q < DD; ++q) { double v = vrow[q]; acc += v*v; }
    float nf = (float)sqrt(acc);
    wTin[((size_t)i*DD + d)*CD + c] = (in_g[i*CD + c] * vrow[d]) / nf;
  } else if (gid < 2*NCB*DD*CD) {
    int e = gid - NCB*DD*CD;
    int i = e / (DD*CD); int rem = e % (DD*CD); int d = rem / CD; int c = rem % CD;
    const float* vrow = out_v + ((size_t)i*DD + d)*CD;    // out_v [NCB][DD][CD]
    double acc = 0.0;
    for (int q = 0; q < CD; ++q) { double v = vrow[q]; acc += v*v; }
    float nf = (float)sqrt(acc);
    wTout[((size_t)i*DD + d)*CD + c] = (out_g[i*DD + d] * vrow[c]) / nf;
  } else if (gid < 2*NCB*DD*CD + NCB*CBK) {
    int e = gid - 2*NCB*DD*CD;
    int i = e / CBK; int k = e % CBK;
    const float* row = cb + ((size_t)i*CBK + k)*CD;
    double acc = 0.0;
    for (int c = 0; c < CD; ++c) { double v = row[c]; acc += v*v; }
    float nf = fmaxf((float)sqrt(acc), 1e-12f);
    float* rec = cbp + ((size_t)i*512 + (k >> 1))*32;
    int h = k & 1;
    float c2 = 0.f;
    for (int c = 0; c < CD; ++c) {
      float cn = row[c] / nf;            // IEEE division, mirrors np
      rec[2*c + h] = cn;
      float s = cn*cn; c2 += s;          // square-then-add (contract off)
    }
    rec[16 + h] = c2;
  }
}

// ---------------------------------------------------------------- main ------
// block = 256 threads (4 waves), 64 t-positions per block.
// Thread (wave wu, lane p) owns residual[d = wu*64 + j][t0+p], j=0..63, in VGPRs.
__launch_bounds__(256, 4)
__global__ void rvq_main(const float* __restrict__ z,
                         const float* __restrict__ in_b, const float* __restrict__ out_b,
                         const float* __restrict__ cb,
                         const int* __restrict__ nqp,
                         const float* __restrict__ wTin, const float* __restrict__ wTout,
                         const float* __restrict__ cbp,
                         float* __restrict__ out, double* __restrict__ lossAcc)
{
#pragma clang fp contract(off)
  const int tid = threadIdx.x;
  const int p   = tid & 63;
  const int wu  = __builtin_amdgcn_readfirstlane(tid >> 6);
  const int blk = blockIdx.x;
  const int b   = blk >> 7;            // 128 t-tiles per batch
  const int t0  = (blk & 127) << 6;
  int nq = *nqp; nq = nq < 0 ? 0 : (nq > NCB ? NCB : nq);

  __shared__ float zep[4][CD][64];   // [wave][channel][pos] -> conflict-free
  __shared__ float bdist[4][64];
  __shared__ int   bkix[4][64];

  const float* zbase = z + ((size_t)b*DD + wu*64)*TT + t0 + p;
  float* zqbase = out + ((size_t)b*DD + wu*64)*TT + t0 + p;

  float r[64];
#pragma unroll
  for (int j = 0; j < 64; ++j) r[j] = zbase[(size_t)j*TT];   // full unroll: VGPRs

  if (nq == 0) {
#pragma unroll
    for (int j = 0; j < 64; ++j) zqbase[(size_t)j*TT] = 0.f;
  }

  double lacc = 0.0;

  for (int i = 0; i < NCB; ++i) {
    // ---- 1. in-projection partials (packed channel pairs; per-channel j-order
    //         identical to scalar version -> bit-exact)
    v2f ze2[4];
#pragma unroll
    for (int h = 0; h < 4; ++h) ze2[h] = (v2f){0.f, 0.f};
    const v2f* wrow2 = (const v2f*)(wTin + ((size_t)i*DD + wu*64)*CD);
#pragma unroll
    for (int j = 0; j < 64; ++j) {
      v2f rv2 = (v2f){r[j], r[j]};
#pragma unroll
      for (int h = 0; h < 4; ++h)
        ze2[h] = __builtin_elementwise_fma(wrow2[j*4 + h], rv2, ze2[h]);
    }
#pragma unroll
    for (int h = 0; h < 4; ++h) {
      zep[wu][2*h    ][p] = ze2[h].x;
      zep[wu][2*h + 1][p] = ze2[h].y;
    }
    __syncthreads();   // BAR A: zep ready (also orders step4 reads vs next step3 writes)

    // ---- 2. reduce + bias + l2norm — ALL waves redundantly, results in registers
    float zef[CD], en[CD];
    float ss = 0.f;
#pragma unroll
    for (int c = 0; c < CD; ++c) {
      float s  = ((zep[0][c][p] + zep[1][c][p]) + zep[2][c][p]) + zep[3][c][p];
      float zf = s + in_b[i*CD + c];
      zef[c] = zf;
      float sq = zf*zf; ss += sq;
    }
    float den = fmaxf(sqrtf(ss), 1e-12f);
    float a2 = 0.f;
#pragma unroll
    for (int c = 0; c < CD; ++c) {
      float e = zef[c] / den;            // IEEE division, mirrors np
      en[c] = e;
      float sq = e*e; a2 += sq;
    }

    // ---- 3. distance scan: 128 code-pairs per wave, v_pk_fma
    //         (each half is an independent sequential chain == scalar rounding)
    v2f enb[CD];
#pragma unroll
    for (int c = 0; c < CD; ++c) enb[c] = (v2f){en[c], en[c]};
    const v2f a2b = (v2f){a2, a2};
    const v2f n2b = (v2f){-2.f, -2.f};
    const v2f* crow = (const v2f*)(cbp + ((size_t)i*512 + wu*128)*32);
    float best = 3.0e38f; int bk = 0;
#pragma unroll 2
    for (int qq = 0; qq < 128; ++qq) {
      const v2f* rw = crow + qq*16;      // uniform -> s_loads
      v2f m = enb[0]*rw[0];
#pragma unroll
      for (int c = 1; c < CD; ++c) m = __builtin_elementwise_fma(enb[c], rw[c], m);
      v2f dd = __builtin_elementwise_fma(n2b, m, a2b);
      dd = dd + rw[8];
      int k0 = (wu*128 + qq)*2;
      bool l0 = dd.x < best; best = l0 ? dd.x : best; bk = l0 ? k0     : bk;
      bool l1 = dd.y < best; best = l1 ? dd.y : best; bk = l1 ? k0 + 1 : bk;
    }
    bdist[wu][p] = best; bkix[wu][p] = bk;
    __syncthreads();   // BAR B: bdist ready (also orders step2 reads vs next step1 writes)

    // ---- 4. argmin combine + gather + STE + loss — ALL waves redundantly
    float bb_ = bdist[0][p]; int k = bkix[0][p];
#pragma unroll
    for (int ww = 1; ww < 4; ++ww) {      // ascending k-ranges, strict <
      float dv = bdist[ww][p]; int kv = bkix[ww][p];
      bool lt = dv < bb_;
      bb_ = lt ? dv : bb_;
      k   = lt ? kv : k;
    }
    const float* qrow = cb + ((size_t)i*CBK + k)*CD;   // raw codebook row (32B aligned)
    v4f qa = ((const v4f*)qrow)[0];
    v4f qb = ((const v4f*)qrow)[1];
    float zc[CD] = {qa.x, qa.y, qa.z, qa.w, qb.x, qb.y, qb.z, qb.w};
    float zst[CD];
    float sloc = 0.f;
#pragma unroll
    for (int c = 0; c < CD; ++c) {
      float zv = zef[c];
      zst[c] = zv + (zc[c] - zv);         // z_e + (z_q_c - z_e), np rounding
      float df = zv - zc[c];
      float sq = df*df; sloc += sq;
    }
    if (wu == 0) {
      if (i < nq) lacc += (double)sloc;
      out[IDX0 + ((size_t)b*NCB + i)*TT + t0 + p] = (float)k;
    }

    // ---- 5. out-projection + residual update (sequential c-chain, as before)
    const float* worow = wTout + ((size_t)i*DD + wu*64)*CD;
    const float* obrow = out_b + i*DD + wu*64;
#pragma unroll
    for (int j = 0; j < 64; ++j) {
      float m = worow[j*CD]*zst[0];
#pragma unroll
      for (int c = 1; c < CD; ++c) m = fmaf(worow[j*CD + c], zst[c], m);
      float zqi = m + obrow[j];
      r[j] -= zqi;
    }
    if (i == nq - 1) {                    // z_q = z - residual_after_nq
#pragma unroll
      for (int j = 0; j < 64; ++j)
        zqbase[(size_t)j*TT] = zbase[(size_t)j*TT] - r[j];
    }
  }

  // ---- loss reduction: wave 0 holds all per-position partials
  if (tid < 64) {
#pragma unroll
    for (int off = 32; off >= 1; off >>= 1) lacc += __shfl_down(lacc, off, 64);
    if (p == 0) atomicAdd(lossAcc, lacc);
  }
}

// ------------------------------------------------------------- finalize -----
__global__ void rvq_fin(const double* __restrict__ lossAcc, float* __restrict__ out) {
  float v = (float)(*lossAcc * (1.0 / 1048576.0));  // / (CD*TT) / BB, 2^20 exact
  out[ZQN]     = v;   // commitment_loss
  out[ZQN + 1] = v;   // codebook_loss (bitwise identical in reference)
}

// ---------------------------------------------------------------- launch ----
extern "C" void kernel_launch(void* const* d_in, const int* in_sizes, int n_in,
                              void* d_out, int out_size, void* d_ws, size_t ws_size,
                              hipStream_t stream) {
  const float* z     = (const float*)d_in[0];
  const float* in_v  = (const float*)d_in[1];
  const float* in_g  = (const float*)d_in[2];
  const float* in_b  = (const float*)d_in[3];
  const float* out_v = (const float*)d_in[4];
  const float* out_g = (const float*)d_in[5];
  const float* out_b = (const float*)d_in[6];
  const float* cb    = (const float*)d_in[7];
  const int*   nqp   = (const int*)d_in[8];
  float* out = (float*)d_out;

  double* lossAcc = (double*)d_ws;
  float* wTin  = (float*)((char*)d_ws + 64);
  float* wTout = wTin  + (size_t)NCB*DD*CD;     // 14336 floats
  float* cbp   = wTout + (size_t)NCB*DD*CD;     // 14336 floats; cbp = 114688 floats

  rvq_prep<<<140, 256, 0, stream>>>(in_v, in_g, out_v, out_g, cb,
                                    wTin, wTout, cbp, lossAcc);
  rvq_main<<<BB * (TT/64), 256, 0, stream>>>(z, in_b, out_b, cb, nqp,
                                             wTin, wTout, cbp, out, lossAcc);
  rvq_fin<<<1, 1, 0, stream>>>(lossAcc, out);
}